// Round 9
// baseline (4626.088 us; speedup 1.0000x reference)
//
#include <hip/hip_runtime.h>
#include <cstdint>
#include <cstddef>

// R9: persistent slice-exchange RNN — dual-ring (fast sc0 L2 + slow MALL).
// 256 WGs = 4 slice-WGs per batch x 64 batches, 512 threads each.
// Writers publish each tagged word TWICE: sc0 store (local XCD L2, fast) and
// agent-scope store (MALL, R4-proven). Readers try the fast ring with a HARD
// CAP of 12 sc0 loads; on failure the lane permanently falls back to the slow
// ring. No unbounded spin on the fast ring -> hang-impossible regardless of
// WG->XCD placement or sc0 semantics.
// Cross-replay safety: every tag carries a per-launch EPOCH (persistent
// counter at ws+0, outside the memset window, bumped by block 0 and broadcast
// via a memset-zeroed cell) -> stale L2/MALL lines from earlier replays can
// never tag-match. Data is tag-validated, so content is route-independent.
// Keeps from R8: bf16-pair packed words, x register prefetch, conflict-free
// out-projection, one barrier per step, no s_sleep in the hot loop.

#define BB 64
#define TT 1024
#define II 64
#define HH 512
#define OO 64
#define FAST_CAP 12

__device__ __forceinline__ float tanh_fast(float v) {
  float e = exp2f(fabsf(v) * 2.8853900817779268f);
  float r = 1.0f - 2.0f * __builtin_amdgcn_rcpf(e + 1.0f);
  return copysignf(r, v);
}
__device__ __forceinline__ unsigned f2bf(float f) {  // RTNE
  unsigned u = __float_as_uint(f);
  return (u + 0x7fffu + ((u >> 16) & 1u)) >> 16;
}
__device__ __forceinline__ float bf2f(unsigned b) {
  return __uint_as_float(b << 16);
}
__device__ __forceinline__ unsigned long long ld_sc0(const unsigned long long* p) {
  unsigned long long v;
  asm volatile("global_load_dwordx2 %0, %1, off sc0\n\ts_waitcnt vmcnt(0)"
               : "=v"(v) : "v"(p) : "memory");
  return v;
}
__device__ __forceinline__ void st_sc0(unsigned long long* p, unsigned long long w) {
  asm volatile("global_store_dwordx2 %0, %1, off sc0"
               :: "v"(p), "v"(w) : "memory");
}

__global__ __launch_bounds__(512, 1) void rnn_persist(
    const float* __restrict__ x, const float* __restrict__ h0,
    const float* __restrict__ Wih, const float* __restrict__ Whh,
    const float* __restrict__ bih, const float* __restrict__ bhh,
    const float* __restrict__ Wout, const float* __restrict__ bout,
    float* __restrict__ out, unsigned long long* __restrict__ epoch_cell,
    unsigned* __restrict__ epoch_bcast,
    unsigned long long* __restrict__ slowring,
    unsigned long long* __restrict__ fastring) {
  const int tid = threadIdx.x;
  const int b   = blockIdx.x & 63;   // batch element
  const int q   = blockIdx.x >> 6;   // slice quarter
  const int n   = tid >> 2;          // local output row 0..127
  const int q4  = tid & 3;           // k-quarter (128 k's each)
  const int row = q * 128 + n;       // global row in H

  __shared__ float h2[2][4][132];
  __shared__ float x2[2][II];
  __shared__ unsigned s_epoch;

  // ---- register-resident weights ----
  float wh[128];
#pragma unroll
  for (int j = 0; j < 32; ++j) {
    const float4 v = *(const float4*)(Whh + (size_t)row * HH + q4 * 128 + j * 4);
    wh[4*j+0] = v.x; wh[4*j+1] = v.y; wh[4*j+2] = v.z; wh[4*j+3] = v.w;
  }
  float wi[16];
#pragma unroll
  for (int j = 0; j < 4; ++j) {
    const float4 v = *(const float4*)(Wih + (size_t)row * II + q4 * 16 + j * 4);
    wi[4*j+0] = v.x; wi[4*j+1] = v.y; wi[4*j+2] = v.z; wi[4*j+3] = v.w;
  }
  const float bias_n = bih[row] + bhh[row];

  // out-proj weights: waves 0-3 only; lane oc covers k=16j+oc (conflict-free)
  const int l     = tid & 63;
  const int oc    = l & 15;
  const int o_loc = (tid >> 6) * 4 + (l >> 4);
  float wo[32];
  float bo = 0.0f;
  if (tid < 256) {
    const int o = q * 16 + o_loc;
#pragma unroll
    for (int j = 0; j < 32; ++j) wo[j] = Wout[(size_t)o * HH + oc + 16 * j];
    bo = bout[o];
  }

  // ---- per-launch epoch: persistent counter + zeroed broadcast cell ----
  if (tid == 0) {
    if (blockIdx.x == 0) {
      unsigned long long old = __hip_atomic_fetch_add(
          epoch_cell, 1ull, __ATOMIC_RELAXED, __HIP_MEMORY_SCOPE_AGENT);
      const unsigned e = (unsigned)old & 0xFFFFFu;
      __hip_atomic_store(epoch_bcast, (e << 1) | 1u,
                         __ATOMIC_RELAXED, __HIP_MEMORY_SCOPE_AGENT);
      s_epoch = e;
    } else {
      unsigned v;
      for (;;) {
        v = __hip_atomic_load(epoch_bcast, __ATOMIC_RELAXED,
                              __HIP_MEMORY_SCOPE_AGENT);
        if (v) break;
        __builtin_amdgcn_s_sleep(4);
      }
      s_epoch = v >> 1;
    }
  }
  __syncthreads();
  const unsigned epoch = s_epoch;

  const float* xb           = x + (size_t)b * TT * II;
  unsigned long long* slowb = slowring + (size_t)b * 2 * 256;
  unsigned long long* fastb = fastring + (size_t)b * 2 * 256;
  float* outb               = out + (size_t)b * TT * OO;

  const bool xloader = (tid >= 256 && tid < 272);
  if (xloader) {
    const int j = tid - 256;
    *(float4*)&x2[1][j * 4] = *(const float4*)(xb + j * 4);
  }

  bool fw = true;  // per-lane: fast ring still trusted

  for (int t = 1; t <= TT + 1; ++t) {
    const int hs = (t - 1) & 1;  // LDS/ring slot holding h_{t-1}

    // prefetch x[t] into registers (consumed at step t+1)
    float4 xv;
    if (t < TT && xloader) {
      xv = *(const float4*)(xb + (size_t)t * II + (tid - 256) * 4);
    }

    // stage h_{t-1}: tid<192 each poll ONE packed word of a sibling quarter
    if (t == 1) {
      if (tid < 256) {
        const int e0 = tid * 2;
        const float2 hv = *(const float2*)(h0 + (size_t)b * HH + e0);
        h2[0][tid >> 6][e0 & 127]       = hv.x;
        h2[0][tid >> 6][(e0 & 127) + 1] = hv.y;
      }
    } else if (tid < 192) {
      const int wq = tid >> 6;
      const int w  = wq + (wq >= q);   // skip own quarter
      const int m  = tid & 63;         // packed rows 2m, 2m+1 of quarter w
      const unsigned want = (epoch << 11) | (unsigned)(t - 1);
      const size_t off = (size_t)hs * 256 + (size_t)w * 64 + m;
      unsigned long long v = 0;
      bool got = false;
      if (fw) {  // bounded fast phase: local-L2 sc0 polls
        for (int k2 = 0; k2 < FAST_CAP; ++k2) {
          v = ld_sc0(fastb + off);
          if ((unsigned)(v >> 32) == want) { got = true; break; }
        }
        if (!got) fw = false;  // permanent per-lane fallback
      }
      if (!got) {  // slow phase: agent-scope at the MALL (R4-proven)
        do {
          v = __hip_atomic_load(slowb + off, __ATOMIC_RELAXED,
                                __HIP_MEMORY_SCOPE_AGENT);
        } while ((unsigned)(v >> 32) != want);
      }
      const unsigned lo = (unsigned)v & 0xffffu;
      const unsigned hi = ((unsigned)v >> 16) & 0xffffu;
      *(float2*)&h2[hs][w][2 * m] = make_float2(bf2f(lo), bf2f(hi));
    }
    __syncthreads();

    // write prefetched x to LDS slot (t+1)&1 — hidden under compute
    if (t < TT && xloader) {
      *(float4*)&x2[(t + 1) & 1][(tid - 256) * 4] = xv;
    }

    if (t <= TT) {
      // ---- recurrent matvec: this thread's 128-k chunk of row `row` ----
      const float* hp = &h2[hs][q4][0];
      float a0 = 0.f, a1 = 0.f, a2 = 0.f, a3 = 0.f;
#pragma unroll
      for (int j = 0; j < 128; j += 4) {
        a0 = fmaf(wh[j+0], hp[j+0], a0);
        a1 = fmaf(wh[j+1], hp[j+1], a1);
        a2 = fmaf(wh[j+2], hp[j+2], a2);
        a3 = fmaf(wh[j+3], hp[j+3], a3);
      }
      // ---- input projection ----
      float ax = 0.f;
      const float* xp = &x2[t & 1][q4 * 16];
#pragma unroll
      for (int j = 0; j < 16; ++j) ax = fmaf(wi[j], xp[j], ax);

      float a = (a0 + a1) + (a2 + a3) + ax;
      a += __shfl_xor(a, 1);
      a += __shfl_xor(a, 2);
      const float hnew = tanh_fast(a + bias_n);
      const float pv   = __shfl_xor(hnew, 4);  // partner row (n^1)
      if (q4 == 0) {
        h2[t & 1][q][n] = hnew;  // own quarter, fp32, straight into next slot
        if ((n & 1) == 0) {
          const unsigned packed = f2bf(hnew) | (f2bf(pv) << 16);
          const unsigned long long word =
              ((unsigned long long)((epoch << 11) | (unsigned)t) << 32) |
              packed;
          const size_t off = (size_t)(t & 1) * 256 + (size_t)q * 64 + (n >> 1);
          st_sc0(fastb + off, word);                     // local L2 (fast)
          __hip_atomic_store(slowb + off, word,          // MALL (guaranteed)
                             __ATOMIC_RELAXED, __HIP_MEMORY_SCOPE_AGENT);
        }
      }
    }

    // ---- out-projection for tau = t-2 (off the critical path) ----
    if (t >= 2 && tid < 256) {
      float s0 = 0.f, s1 = 0.f;
#pragma unroll
      for (int j = 0; j < 32; j += 2) {
        s0 = fmaf(wo[j+0], h2[hs][(j+0) >> 3][oc + 16 * ((j+0) & 7)], s0);
        s1 = fmaf(wo[j+1], h2[hs][(j+1) >> 3][oc + 16 * ((j+1) & 7)], s1);
      }
      float s = s0 + s1;
      s += __shfl_xor(s, 1);
      s += __shfl_xor(s, 2);
      s += __shfl_xor(s, 4);
      s += __shfl_xor(s, 8);
      if (oc == 0) {
        outb[(size_t)(t - 2) * OO + q * 16 + o_loc] = tanh_fast(s + bo);
      }
    }

    // ---- final hidden state h_T -> d_out tail ----
    if (t == TT + 1 && q == 0 && tid < 256) {
      const int e0 = tid * 2;
      float* hout = out + (size_t)BB * TT * OO + (size_t)b * HH + e0;
      hout[0] = h2[hs][e0 >> 7][e0 & 127];
      hout[1] = h2[hs][e0 >> 7][(e0 & 127) + 1];
    }
  }
}

extern "C" void kernel_launch(void* const* d_in, const int* in_sizes, int n_in,
                              void* d_out, int out_size, void* d_ws, size_t ws_size,
                              hipStream_t stream) {
  (void)in_sizes; (void)n_in; (void)out_size; (void)ws_size;
  const float* x    = (const float*)d_in[0];
  const float* h0   = (const float*)d_in[1];
  const float* Wih  = (const float*)d_in[2];
  const float* Whh  = (const float*)d_in[3];
  const float* bih  = (const float*)d_in[4];
  const float* bhh  = (const float*)d_in[5];
  const float* Wout = (const float*)d_in[6];
  const float* bout = (const float*)d_in[7];
  float* out = (float*)d_out;

  unsigned char* ws = (unsigned char*)d_ws;
  // layout: [0]   epoch_cell   (8B, PERSISTENT — never memset)
  //         [256] epoch_bcast  (4B, zeroed every launch)
  //         [4096]          slow ring: 64b x 2 x 256 x 8B = 256 KB (zeroed)
  //         [4096 + 256KB]  fast ring: same size (epoch-tag protected)
  unsigned long long* epoch_cell = (unsigned long long*)ws;
  unsigned* epoch_bcast          = (unsigned*)(ws + 256);
  unsigned long long* slowring   = (unsigned long long*)(ws + 4096);
  unsigned long long* fastring   = (unsigned long long*)(ws + 4096 + 262144);

  // zero broadcast cell + slow-ring tags each (replayed) launch
  hipMemsetAsync(ws + 256, 0, 4096 - 256 + 262144, stream);

  rnn_persist<<<dim3(256), dim3(512), 0, stream>>>(
      x, h0, Wih, Whh, bih, bhh, Wout, bout, out,
      epoch_cell, epoch_bcast, slowring, fastring);
}